// Round 2
// baseline (578.396 us; speedup 1.0000x reference)
//
#include <hip/hip_runtime.h>
#include <hip/hip_bf16.h>
#include <math.h>

// Problem constants
#define BB 8
#define LLEN 1024
#define DDIM 512
#define HH 8
#define DLAT 512
#define NROW (BB * LLEN)        // 8192
#define ROWELEM 4194304         // 8192*512

typedef __bf16 bf16x8 __attribute__((ext_vector_type(8)));
typedef __bf16 bf16x4 __attribute__((ext_vector_type(4)));
typedef float  f32x4  __attribute__((ext_vector_type(4)));

__device__ inline __bf16 f2bf(float f) {
    union { float f; unsigned u; } a; a.f = f;
    unsigned r = (a.u + 0x7fffu + ((a.u >> 16) & 1u)) >> 16;
    union { unsigned short s; __bf16 b; } o; o.s = (unsigned short)r;
    return o.b;
}

// ---------------------------------------------------------------------------
// Weight transpose + cast (3 weights in one launch): W[K][N] -> WT[N][K] bf16
// ---------------------------------------------------------------------------
__global__ __launch_bounds__(256) void wtrans3_kernel(
    const float* __restrict__ W0, const float* __restrict__ W1,
    const float* __restrict__ W2, __bf16* __restrict__ T0,
    __bf16* __restrict__ T1, __bf16* __restrict__ T2)
{
    const float* W = (blockIdx.y == 0) ? W0 : (blockIdx.y == 1) ? W1 : W2;
    __bf16* WT     = (blockIdx.y == 0) ? T0 : (blockIdx.y == 1) ? T1 : T2;

    __shared__ float t[64][65];
    const int tid = threadIdx.x;
    const int bx = blockIdx.x & 7;        // col tile (N)
    const int by = blockIdx.x >> 3;       // row tile (K)
    const int r0 = by * 64, c0 = bx * 64;

    #pragma unroll
    for (int p = 0; p < 4; ++p) {
        int r = p * 16 + (tid >> 4);
        int c = (tid & 15) * 4;
        f32x4 v = *(const f32x4*)(W + (size_t)(r0 + r) * 512 + c0 + c);
        t[r][c] = v[0]; t[r][c + 1] = v[1]; t[r][c + 2] = v[2]; t[r][c + 3] = v[3];
    }
    __syncthreads();
    #pragma unroll
    for (int p = 0; p < 4; ++p) {
        int c = p * 16 + (tid >> 4);
        int rc = (tid & 15) * 4;
        bf16x4 o;
        #pragma unroll
        for (int m = 0; m < 4; ++m) o[m] = f2bf(t[rc + m][c]);
        *(bf16x4*)(WT + (size_t)(c0 + c) * 512 + r0 + rc) = o;
    }
}

// hi/lo split variant (2 weights in one launch)
__global__ __launch_bounds__(256) void wtrans_hilo2_kernel(
    const float* __restrict__ W0, const float* __restrict__ W1,
    __bf16* __restrict__ H0, __bf16* __restrict__ L0,
    __bf16* __restrict__ H1, __bf16* __restrict__ L1)
{
    const float* W  = (blockIdx.y == 0) ? W0 : W1;
    __bf16* WTh     = (blockIdx.y == 0) ? H0 : H1;
    __bf16* WTl     = (blockIdx.y == 0) ? L0 : L1;

    __shared__ float t[64][65];
    const int tid = threadIdx.x;
    const int bx = blockIdx.x & 7;
    const int by = blockIdx.x >> 3;
    const int r0 = by * 64, c0 = bx * 64;

    #pragma unroll
    for (int p = 0; p < 4; ++p) {
        int r = p * 16 + (tid >> 4);
        int c = (tid & 15) * 4;
        f32x4 v = *(const f32x4*)(W + (size_t)(r0 + r) * 512 + c0 + c);
        t[r][c] = v[0]; t[r][c + 1] = v[1]; t[r][c + 2] = v[2]; t[r][c + 3] = v[3];
    }
    __syncthreads();
    #pragma unroll
    for (int p = 0; p < 4; ++p) {
        int c = p * 16 + (tid >> 4);
        int rc = (tid & 15) * 4;
        bf16x4 oh, ol;
        #pragma unroll
        for (int m = 0; m < 4; ++m) {
            float v = t[rc + m][c];
            __bf16 hi = f2bf(v);
            oh[m] = hi;
            ol[m] = f2bf(v - (float)hi);
        }
        *(bf16x4*)(WTh + (size_t)(c0 + c) * 512 + r0 + rc) = oh;
        *(bf16x4*)(WTl + (size_t)(c0 + c) * 512 + r0 + rc) = ol;
    }
}

// ---------------------------------------------------------------------------
// MFMA GEMM (QK): C_bf16[M,512] = bf16(A_f32[M,512]) @ Bt[512,512]^T + bias
// BM=128 BN=64 BK=64; 256 thr = 4 waves (2m x 2n); wave tile 64x32.
// ---------------------------------------------------------------------------
__global__ __launch_bounds__(256) void gemm_qkv_mfma(
    const float* __restrict__ A, const __bf16* __restrict__ Bt,
    const float* __restrict__ bias, __bf16* __restrict__ C)
{
    const int tid  = threadIdx.x;
    const int w    = tid >> 6, lane = tid & 63;
    const int quad = lane >> 4, lid = lane & 15;
    const int wm = w >> 1, wn = w & 1;
    const int col0 = blockIdx.x * 64;
    const int row0 = blockIdx.y * 128;

    __shared__ __bf16 As[128][72];
    __shared__ __bf16 Bs[64][72];

    const f32x4 zero = {0.f, 0.f, 0.f, 0.f};
    f32x4 acc[4][2];
    #pragma unroll
    for (int i = 0; i < 4; ++i)
        #pragma unroll
        for (int j = 0; j < 2; ++j) acc[i][j] = zero;

    for (int kt = 0; kt < 512; kt += 64) {
        __syncthreads();
        {
            const int rr = lane >> 4;
            const int cc = lane & 15;
            #pragma unroll
            for (int p = 0; p < 8; ++p) {
                int r = w * 32 + p * 4 + rr;
                f32x4 v = *(const f32x4*)(A + (size_t)(row0 + r) * 512 + kt + cc * 4);
                bf16x4 o;
                #pragma unroll
                for (int m = 0; m < 4; ++m) o[m] = f2bf(v[m]);
                *(bf16x4*)&As[r][cc * 4] = o;
            }
        }
        {
            const int rr = lane >> 3;
            const int cc = lane & 7;
            #pragma unroll
            for (int p = 0; p < 2; ++p) {
                int r = w * 16 + p * 8 + rr;
                *(bf16x8*)&Bs[r][cc * 8] =
                    *(const bf16x8*)(Bt + (size_t)(col0 + r) * 512 + kt + cc * 8);
            }
        }
        __syncthreads();
        #pragma unroll
        for (int ks = 0; ks < 2; ++ks) {
            bf16x8 a[4], b[2];
            #pragma unroll
            for (int i = 0; i < 4; ++i)
                a[i] = *(const bf16x8*)&As[wm * 64 + i * 16 + lid][ks * 32 + quad * 8];
            #pragma unroll
            for (int j = 0; j < 2; ++j)
                b[j] = *(const bf16x8*)&Bs[wn * 32 + j * 16 + lid][ks * 32 + quad * 8];
            #pragma unroll
            for (int i = 0; i < 4; ++i)
                #pragma unroll
                for (int j = 0; j < 2; ++j)
                    acc[i][j] = __builtin_amdgcn_mfma_f32_16x16x32_bf16(a[i], b[j], acc[i][j], 0, 0, 0);
        }
    }

    float bcol[2];
    #pragma unroll
    for (int j = 0; j < 2; ++j) bcol[j] = bias[col0 + wn * 32 + j * 16 + lid];
    #pragma unroll
    for (int i = 0; i < 4; ++i)
        #pragma unroll
        for (int j = 0; j < 2; ++j) {
            int colg = col0 + wn * 32 + j * 16 + lid;
            #pragma unroll
            for (int r = 0; r < 4; ++r) {
                int rowg = row0 + wm * 64 + i * 16 + quad * 4 + r;
                C[(size_t)rowg * 512 + colg] = f2bf(acc[i][j][r] + bcol[j]);
            }
        }
}

// ---------------------------------------------------------------------------
// V projection with fused transpose epilogue: writes VtG[b,h,d,l] directly.
// Same K-loop as gemm_qkv; epilogue transposes the 128(l) x 64(d) tile via LDS.
// ---------------------------------------------------------------------------
__global__ __launch_bounds__(256) void gemm_v_mfma(
    const float* __restrict__ A, const __bf16* __restrict__ Bt,
    const float* __restrict__ bias, __bf16* __restrict__ VtG)
{
    const int tid  = threadIdx.x;
    const int w    = tid >> 6, lane = tid & 63;
    const int quad = lane >> 4, lid = lane & 15;
    const int wm = w >> 1, wn = w & 1;
    const int col0 = blockIdx.x * 64;
    const int row0 = blockIdx.y * 128;

    __shared__ __bf16 As[128][72];
    __shared__ __bf16 Bs[64][72];

    const f32x4 zero = {0.f, 0.f, 0.f, 0.f};
    f32x4 acc[4][2];
    #pragma unroll
    for (int i = 0; i < 4; ++i)
        #pragma unroll
        for (int j = 0; j < 2; ++j) acc[i][j] = zero;

    for (int kt = 0; kt < 512; kt += 64) {
        __syncthreads();
        {
            const int rr = lane >> 4;
            const int cc = lane & 15;
            #pragma unroll
            for (int p = 0; p < 8; ++p) {
                int r = w * 32 + p * 4 + rr;
                f32x4 v = *(const f32x4*)(A + (size_t)(row0 + r) * 512 + kt + cc * 4);
                bf16x4 o;
                #pragma unroll
                for (int m = 0; m < 4; ++m) o[m] = f2bf(v[m]);
                *(bf16x4*)&As[r][cc * 4] = o;
            }
        }
        {
            const int rr = lane >> 3;
            const int cc = lane & 7;
            #pragma unroll
            for (int p = 0; p < 2; ++p) {
                int r = w * 16 + p * 8 + rr;
                *(bf16x8*)&Bs[r][cc * 8] =
                    *(const bf16x8*)(Bt + (size_t)(col0 + r) * 512 + kt + cc * 8);
            }
        }
        __syncthreads();
        #pragma unroll
        for (int ks = 0; ks < 2; ++ks) {
            bf16x8 a[4], b[2];
            #pragma unroll
            for (int i = 0; i < 4; ++i)
                a[i] = *(const bf16x8*)&As[wm * 64 + i * 16 + lid][ks * 32 + quad * 8];
            #pragma unroll
            for (int j = 0; j < 2; ++j)
                b[j] = *(const bf16x8*)&Bs[wn * 32 + j * 16 + lid][ks * 32 + quad * 8];
            #pragma unroll
            for (int i = 0; i < 4; ++i)
                #pragma unroll
                for (int j = 0; j < 2; ++j)
                    acc[i][j] = __builtin_amdgcn_mfma_f32_16x16x32_bf16(a[i], b[j], acc[i][j], 0, 0, 0);
        }
    }

    // transpose epilogue through LDS (reuse As storage: 64x136 <= 128x72)
    __syncthreads();
    __bf16 (*Ts)[136] = (__bf16 (*)[136])(&As[0][0]);
    float bcol[2];
    #pragma unroll
    for (int j = 0; j < 2; ++j) bcol[j] = bias[col0 + wn * 32 + j * 16 + lid];
    #pragma unroll
    for (int i = 0; i < 4; ++i)
        #pragma unroll
        for (int j = 0; j < 2; ++j) {
            int d = wn * 32 + j * 16 + lid;
            #pragma unroll
            for (int r = 0; r < 4; ++r) {
                int l = wm * 64 + i * 16 + quad * 4 + r;
                Ts[d][l] = f2bf(acc[i][j][r] + bcol[j]);
            }
        }
    __syncthreads();
    const int b = row0 >> 10, l0 = row0 & 1023, h = blockIdx.x;
    const size_t obase = (size_t)((b * 8 + h) * 64) * LLEN;
    #pragma unroll
    for (int p = 0; p < 4; ++p) {
        int cix = tid + p * 256;
        int d = cix >> 4, lc = cix & 15;
        bf16x8 vv = *(const bf16x8*)&Ts[d][lc * 8];
        *(bf16x8*)(VtG + obase + (size_t)d * LLEN + l0 + lc * 8) = vv;
    }
}

// ---------------------------------------------------------------------------
// Split-bf16 3-pass MFMA GEMM, BK=32 (30KB LDS -> 4-5 blocks/CU)
// ---------------------------------------------------------------------------
__global__ __launch_bounds__(256) void gemm_split_mfma(
    const __bf16* __restrict__ Ahi, const __bf16* __restrict__ Alo,
    const __bf16* __restrict__ Bth, const __bf16* __restrict__ Btl,
    const float* __restrict__ bias, float* __restrict__ C)
{
    const int tid  = threadIdx.x;
    const int w    = tid >> 6, lane = tid & 63;
    const int quad = lane >> 4, lid = lane & 15;
    const int wm = w >> 1, wn = w & 1;
    const int col0 = blockIdx.x * 64;
    const int row0 = blockIdx.y * 128;

    __shared__ __bf16 Ah[128][40];
    __shared__ __bf16 Al[128][40];
    __shared__ __bf16 Bh[64][40];
    __shared__ __bf16 Bl[64][40];

    const f32x4 zero = {0.f, 0.f, 0.f, 0.f};
    f32x4 acc[4][2];
    #pragma unroll
    for (int i = 0; i < 4; ++i)
        #pragma unroll
        for (int j = 0; j < 2; ++j) acc[i][j] = zero;

    for (int kt = 0; kt < 512; kt += 32) {
        __syncthreads();
        #pragma unroll
        for (int p = 0; p < 2; ++p) {
            int cix = tid + p * 256;
            int r = cix >> 2, cc = cix & 3;
            size_t g = (size_t)(row0 + r) * 512 + kt + cc * 8;
            *(bf16x8*)&Ah[r][cc * 8] = *(const bf16x8*)(Ahi + g);
            *(bf16x8*)&Al[r][cc * 8] = *(const bf16x8*)(Alo + g);
        }
        {
            int r = tid >> 2, cc = tid & 3;
            size_t g = (size_t)(col0 + r) * 512 + kt + cc * 8;
            *(bf16x8*)&Bh[r][cc * 8] = *(const bf16x8*)(Bth + g);
            *(bf16x8*)&Bl[r][cc * 8] = *(const bf16x8*)(Btl + g);
        }
        __syncthreads();
        bf16x8 ah[4], al[4], bh[2], bl[2];
        #pragma unroll
        for (int i = 0; i < 4; ++i) {
            ah[i] = *(const bf16x8*)&Ah[wm * 64 + i * 16 + lid][quad * 8];
            al[i] = *(const bf16x8*)&Al[wm * 64 + i * 16 + lid][quad * 8];
        }
        #pragma unroll
        for (int j = 0; j < 2; ++j) {
            bh[j] = *(const bf16x8*)&Bh[wn * 32 + j * 16 + lid][quad * 8];
            bl[j] = *(const bf16x8*)&Bl[wn * 32 + j * 16 + lid][quad * 8];
        }
        #pragma unroll
        for (int i = 0; i < 4; ++i)
            #pragma unroll
            for (int j = 0; j < 2; ++j) {
                f32x4 t = __builtin_amdgcn_mfma_f32_16x16x32_bf16(al[i], bh[j], acc[i][j], 0, 0, 0);
                t = __builtin_amdgcn_mfma_f32_16x16x32_bf16(ah[i], bl[j], t, 0, 0, 0);
                acc[i][j] = __builtin_amdgcn_mfma_f32_16x16x32_bf16(ah[i], bh[j], t, 0, 0, 0);
            }
    }

    float bcol[2];
    #pragma unroll
    for (int j = 0; j < 2; ++j) bcol[j] = bias[col0 + wn * 32 + j * 16 + lid];
    #pragma unroll
    for (int i = 0; i < 4; ++i)
        #pragma unroll
        for (int j = 0; j < 2; ++j) {
            int colg = col0 + wn * 32 + j * 16 + lid;
            #pragma unroll
            for (int r = 0; r < 4; ++r) {
                int rowg = row0 + wm * 64 + i * 16 + quad * 4 + r;
                C[(size_t)rowg * 512 + colg] = acc[i][j][r] + bcol[j];
            }
        }
}

// ---------------------------------------------------------------------------
// FiLM latent
// ---------------------------------------------------------------------------
__global__ __launch_bounds__(256) void film_latent_kernel(
    const float* __restrict__ latent, const float* __restrict__ Ws1,
    const float* __restrict__ bs1, float* __restrict__ film)
{
    __shared__ float sl[DLAT];
    const int b = blockIdx.x;
    const int tid = threadIdx.x;
    #pragma unroll
    for (int l = 0; l < 2; ++l) {
        int k = tid + l * 256;
        float x = latent[b * DLAT + k];
        sl[k] = x / (1.f + __expf(-x));
    }
    __syncthreads();
    int n = blockIdx.y * 256 + tid;
    float acc = bs1[n];
    for (int k = 0; k < DLAT; ++k)
        acc += sl[k] * Ws1[(size_t)k * 1024 + n];
    film[b * 1024 + n] = acc;
}

// ---------------------------------------------------------------------------
// MFMA attention, double-buffered + async-STAGE (T14) + NT attn stores.
// 1 barrier/tile (was 2-3); mid-pass2 barrier replaced by lgkmcnt fence
// (PtS is per-wave; only LDS ordering is needed, not a vmcnt(0) drain).
// ---------------------------------------------------------------------------
__global__ __launch_bounds__(256) void attn_mfma_kernel(
    const __bf16* __restrict__ Qb, const __bf16* __restrict__ Kb,
    const __bf16* __restrict__ VtG, float* __restrict__ attn_out,
    __bf16* __restrict__ Ohi, __bf16* __restrict__ Olo)
{
    const int bid = blockIdx.x;
    const int qt = bid & 15;
    const int h  = (bid >> 4) & 7;
    const int b  = bid >> 7;
    const int q0 = qt * 64;
    const int tid = threadIdx.x;
    const int w    = tid >> 6;
    const int lane = tid & 63;
    const int quad = lane >> 4;
    const int lid  = lane & 15;

    __shared__ __bf16 KtS[2][64][72];
    __shared__ __bf16 VtS[2][64][72];
    __shared__ __bf16 PtS[4][16][72];

    const int myq = q0 + w * 16 + lid;
    const __bf16* qptr = Qb + (size_t)(b * LLEN + myq) * DDIM + h * 64 + quad * 8;
    const bf16x8 qf0 = *(const bf16x8*)(qptr);
    const bf16x8 qf1 = *(const bf16x8*)(qptr + 32);

    const size_t kbase = (size_t)(b * LLEN) * DDIM + h * 64;
    const size_t vbase = (size_t)((b * 8 + h) * 64) * LLEN;
    const f32x4 zero = {0.f, 0.f, 0.f, 0.f};
    const float C0 = 0.125f;

    const int sr = tid >> 3;      // 0..31 staging row
    const int sc = tid & 7;       // 0..7  staging 16B chunk

    // ---------------- pass 1: row sums ----------------
    // prologue: tile 0 -> buf 0
    #pragma unroll
    for (int rep = 0; rep < 2; ++rep) {
        int r = sr + rep * 32;
        *(bf16x8*)&KtS[0][r][sc * 8] =
            *(const bf16x8*)(Kb + kbase + (size_t)r * DDIM + sc * 8);
    }
    __syncthreads();

    float rsum = 0.f;
    int cur = 0;
    for (int kt = 0; kt < 16; ++kt) {
        bf16x8 kr0, kr1;
        if (kt < 15) {
            kr0 = *(const bf16x8*)(Kb + kbase + (size_t)((kt + 1) * 64 + sr) * DDIM + sc * 8);
            kr1 = *(const bf16x8*)(Kb + kbase + (size_t)((kt + 1) * 64 + sr + 32) * DDIM + sc * 8);
        }
        #pragma unroll
        for (int st = 0; st < 4; ++st) {
            bf16x8 a0 = *(const bf16x8*)&KtS[cur][st * 16 + lid][quad * 8];
            bf16x8 a1 = *(const bf16x8*)&KtS[cur][st * 16 + lid][32 + quad * 8];
            f32x4 c = __builtin_amdgcn_mfma_f32_16x16x32_bf16(a0, qf0, zero, 0, 0, 0);
            c = __builtin_amdgcn_mfma_f32_16x16x32_bf16(a1, qf1, c, 0, 0, 0);
            #pragma unroll
            for (int r = 0; r < 4; ++r) rsum += __expf(C0 * c[r]);
        }
        if (kt < 15) {
            *(bf16x8*)&KtS[cur ^ 1][sr][sc * 8] = kr0;
            *(bf16x8*)&KtS[cur ^ 1][sr + 32][sc * 8] = kr1;
        }
        __syncthreads();
        cur ^= 1;
    }
    rsum += __shfl_xor(rsum, 16, 64);
    rsum += __shfl_xor(rsum, 32, 64);
    const float rinv = 1.f / rsum;

    // ---------------- pass 2: attn write + PV ----------------
    f32x4 oacc[4] = {zero, zero, zero, zero};
    const size_t abase = ((size_t)((b * 8 + h) * LLEN + myq)) * LLEN;

    // prologue: tile 0 -> buf 0 (K and V)
    #pragma unroll
    for (int rep = 0; rep < 2; ++rep) {
        int r = sr + rep * 32;
        *(bf16x8*)&KtS[0][r][sc * 8] =
            *(const bf16x8*)(Kb + kbase + (size_t)r * DDIM + sc * 8);
        *(bf16x8*)&VtS[0][r][sc * 8] =
            *(const bf16x8*)(VtG + vbase + (size_t)r * LLEN + sc * 8);
    }
    __syncthreads();

    cur = 0;
    for (int kt = 0; kt < 16; ++kt) {
        bf16x8 kr0, kr1, vr0, vr1;
        if (kt < 15) {
            kr0 = *(const bf16x8*)(Kb + kbase + (size_t)((kt + 1) * 64 + sr) * DDIM + sc * 8);
            kr1 = *(const bf16x8*)(Kb + kbase + (size_t)((kt + 1) * 64 + sr + 32) * DDIM + sc * 8);
            vr0 = *(const bf16x8*)(VtG + vbase + (size_t)sr * LLEN + (kt + 1) * 64 + sc * 8);
            vr1 = *(const bf16x8*)(VtG + vbase + (size_t)(sr + 32) * LLEN + (kt + 1) * 64 + sc * 8);
        }
        #pragma unroll
        for (int st = 0; st < 4; ++st) {
            bf16x8 a0 = *(const bf16x8*)&KtS[cur][st * 16 + lid][quad * 8];
            bf16x8 a1 = *(const bf16x8*)&KtS[cur][st * 16 + lid][32 + quad * 8];
            f32x4 c = __builtin_amdgcn_mfma_f32_16x16x32_bf16(a0, qf0, zero, 0, 0, 0);
            c = __builtin_amdgcn_mfma_f32_16x16x32_bf16(a1, qf1, c, 0, 0, 0);
            f32x4 p;
            bf16x4 pk;
            #pragma unroll
            for (int r = 0; r < 4; ++r) {
                p[r] = __expf(C0 * c[r]) * rinv;
                pk[r] = f2bf(p[r]);
            }
            __builtin_nontemporal_store(p, (f32x4*)(attn_out + abase + kt * 64 + st * 16 + quad * 4));
            *(bf16x4*)&PtS[w][lid][st * 16 + quad * 4] = pk;
        }
        // PtS is per-wave: order LDS writes before cross-lane reads without
        // draining vmcnt (keeps the prefetch loads + NT stores in flight)
        asm volatile("s_waitcnt lgkmcnt(0)" ::: "memory");
        #pragma unroll
        for (int kc = 0; kc < 2; ++kc) {
            bf16x8 pa = *(const bf16x8*)&PtS[w][lid][kc * 32 + quad * 8];
            #pragma unroll
            for (int nt = 0; nt < 4; ++nt) {
                bf16x8 vb = *(const bf16x8*)&VtS[cur][nt * 16 + lid][kc * 32 + quad * 8];
                oacc[nt] = __builtin_amdgcn_mfma_f32_16x16x32_bf16(pa, vb, oacc[nt], 0, 0, 0);
            }
        }
        if (kt < 15) {
            *(bf16x8*)&KtS[cur ^ 1][sr][sc * 8] = kr0;
            *(bf16x8*)&KtS[cur ^ 1][sr + 32][sc * 8] = kr1;
            *(bf16x8*)&VtS[cur ^ 1][sr][sc * 8] = vr0;
            *(bf16x8*)&VtS[cur ^ 1][sr + 32][sc * 8] = vr1;
        }
        __syncthreads();
        cur ^= 1;
    }

    // O epilogue: hi/lo bf16 split
    #pragma unroll
    for (int nt = 0; nt < 4; ++nt)
        #pragma unroll
        for (int r = 0; r < 4; ++r) {
            float val = oacc[nt][r];
            __bf16 hi = f2bf(val);
            size_t idx = (size_t)(b * LLEN + q0 + w * 16 + quad * 4 + r) * DDIM + h * 64 + nt * 16 + lid;
            Ohi[idx] = hi;
            Olo[idx] = f2bf(val - (float)hi);
        }
}

// ---------------------------------------------------------------------------
__device__ inline void block_reduce2(float& a, float& b) {
    #pragma unroll
    for (int off = 32; off > 0; off >>= 1) {
        a += __shfl_down(a, off, 64);
        b += __shfl_down(b, off, 64);
    }
    __shared__ float wa[4], wb[4];
    int lane = threadIdx.x & 63, w = threadIdx.x >> 6;
    if (lane == 0) { wa[w] = a; wb[w] = b; }
    __syncthreads();
    if (threadIdx.x == 0) {
        wa[0] = wa[0] + wa[1] + wa[2] + wa[3];
        wb[0] = wb[0] + wb[1] + wb[2] + wb[3];
    }
    __syncthreads();
    a = wa[0];
    b = wb[0];
}

__global__ __launch_bounds__(256) void film_ln_kernel(
    const float* __restrict__ X, const float* __restrict__ en_g,
    const float* __restrict__ en_b, const float* __restrict__ film,
    __bf16* __restrict__ HShi, __bf16* __restrict__ HSlo)
{
    const int row = blockIdx.x;
    const int b = row >> 10;
    const int tid = threadIdx.x;
    const size_t base = (size_t)row * DDIM;

    float x0 = X[base + tid];
    float x1 = X[base + 256 + tid];
    float s = x0 + x1;
    float s2 = x0 * x0 + x1 * x1;
    block_reduce2(s, s2);
    float mean = s * (1.f / 512.f);
    float var = s2 * (1.f / 512.f) - mean * mean;
    float inv = rsqrtf(var + 1e-5f);

    #pragma unroll
    for (int l = 0; l < 2; ++l) {
        int d = tid + l * 256;
        float x = (l == 0) ? x0 : x1;
        float nh = (x - mean) * inv * en_g[d] + en_b[d];
        float sc = film[b * 1024 + d];
        float sh = film[b * 1024 + 512 + d];
        float hv = nh * (1.f + sc) + sh;
        float sv = hv / (1.f + __expf(-hv));
        __bf16 hi = f2bf(sv);
        HShi[base + d] = hi;
        HSlo[base + d] = f2bf(sv - (float)hi);
    }
}

__global__ __launch_bounds__(256) void final_ln_kernel(
    const float* __restrict__ H2, const float* __restrict__ resid,
    const float* __restrict__ g, const float* __restrict__ bta,
    float* __restrict__ out)
{
    const int row = blockIdx.x;
    const int tid = threadIdx.x;
    const size_t base = (size_t)row * DDIM;

    float x0 = H2[base + tid] + resid[base + tid];
    float x1 = H2[base + 256 + tid] + resid[base + 256 + tid];
    float s = x0 + x1;
    float s2 = x0 * x0 + x1 * x1;
    block_reduce2(s, s2);
    float mean = s * (1.f / 512.f);
    float var = s2 * (1.f / 512.f) - mean * mean;
    float inv = rsqrtf(var + 1e-6f);

    #pragma unroll
    for (int l = 0; l < 2; ++l) {
        int d = tid + l * 256;
        float x = (l == 0) ? x0 : x1;
        float o = (x - mean) * inv * g[d] + bta[d];
        __builtin_nontemporal_store(o, out + base + d);
    }
}

// ---------------------------------------------------------------------------
extern "C" void kernel_launch(void* const* d_in, const int* in_sizes, int n_in,
                              void* d_out, int out_size, void* d_ws, size_t ws_size,
                              hipStream_t stream)
{
    const float* q      = (const float*)d_in[0];
    const float* k      = (const float*)d_in[1];
    const float* v      = (const float*)d_in[2];
    const float* latent = (const float*)d_in[3];
    const float* Wq  = (const float*)d_in[4];
    const float* bq  = (const float*)d_in[5];
    const float* Wk  = (const float*)d_in[6];
    const float* bk  = (const float*)d_in[7];
    const float* Wv  = (const float*)d_in[8];
    const float* bv  = (const float*)d_in[9];
    const float* Wfc = (const float*)d_in[10];
    const float* bfc = (const float*)d_in[11];
    const float* Ws1 = (const float*)d_in[12];
    const float* bs1 = (const float*)d_in[13];
    const float* Ws2 = (const float*)d_in[14];
    const float* bs2 = (const float*)d_in[15];
    const float* en_g = (const float*)d_in[16];
    const float* en_b = (const float*)d_in[17];
    const float* ln_g = (const float*)d_in[18];
    const float* ln_b = (const float*)d_in[19];

    float* out  = (float*)d_out;            // [8192, 512]
    float* attn = out + ROWELEM;            // [8, 8, 1024, 1024]

    char* ws = (char*)d_ws;
    __bf16* Qb   = (__bf16*)(ws + 0);              // 8.4 MB
    __bf16* Kb   = (__bf16*)(ws + 8388608);
    __bf16* VtG  = (__bf16*)(ws + 16777216);
    __bf16* Ohi  = (__bf16*)(ws + 25165824);
    __bf16* Olo  = (__bf16*)(ws + 33554432);
    __bf16* WqT  = (__bf16*)(ws + 41943040);       // 512 KB each
    __bf16* WkT  = (__bf16*)(ws + 42467328);
    __bf16* WvT  = (__bf16*)(ws + 42991616);
    __bf16* WfhT = (__bf16*)(ws + 43515904);
    __bf16* WflT = (__bf16*)(ws + 44040192);
    __bf16* W2hT = (__bf16*)(ws + 44564480);
    __bf16* W2lT = (__bf16*)(ws + 45088768);
    float*  film = (float*)(ws + 45613056);        // 32 KB

    // aliases over dead regions:
    float*  F1   = (float*)(ws + 0);               // over Qb+Kb (dead after attn)
    __bf16* HShi = Ohi;                            // O dead after FC gemm
    __bf16* HSlo = Olo;
    float*  H2   = (float*)(ws + 0);               // over F1 (dead after film_ln)

    wtrans3_kernel<<<dim3(64, 3), 256, 0, stream>>>(Wq, Wk, Wv, WqT, WkT, WvT);
    wtrans_hilo2_kernel<<<dim3(64, 2), 256, 0, stream>>>(Wfc, Ws2, WfhT, WflT, W2hT, W2lT);
    film_latent_kernel<<<dim3(BB, 4), 256, 0, stream>>>(latent, Ws1, bs1, film);

    dim3 ggrid(8, 64);   // N/64 x M/128
    gemm_qkv_mfma<<<ggrid, 256, 0, stream>>>(q, WqT, bq, Qb);
    gemm_qkv_mfma<<<ggrid, 256, 0, stream>>>(k, WkT, bk, Kb);
    gemm_v_mfma<<<ggrid, 256, 0, stream>>>(v, WvT, bv, VtG);

    attn_mfma_kernel<<<1024, 256, 0, stream>>>(Qb, Kb, VtG, attn, Ohi, Olo);

    gemm_split_mfma<<<ggrid, 256, 0, stream>>>(Ohi, Olo, WfhT, WflT, bfc, F1);
    film_ln_kernel<<<NROW, 256, 0, stream>>>(F1, en_g, en_b, film, HShi, HSlo);
    gemm_split_mfma<<<ggrid, 256, 0, stream>>>(HShi, HSlo, W2hT, W2lT, bs2, H2);
    final_ln_kernel<<<NROW, 256, 0, stream>>>(H2, q, ln_g, ln_b, out);
}

// Round 3
// 531.815 us; speedup vs baseline: 1.0876x; 1.0876x over previous
//
#include <hip/hip_runtime.h>
#include <hip/hip_bf16.h>
#include <math.h>

// Problem constants
#define BB 8
#define LLEN 1024
#define DDIM 512
#define HH 8
#define DLAT 512
#define NROW (BB * LLEN)        // 8192
#define ROWELEM 4194304         // 8192*512

typedef __bf16 bf16x8 __attribute__((ext_vector_type(8)));
typedef __bf16 bf16x4 __attribute__((ext_vector_type(4)));
typedef float  f32x4  __attribute__((ext_vector_type(4)));

__device__ inline __bf16 f2bf(float f) {
    union { float f; unsigned u; } a; a.f = f;
    unsigned r = (a.u + 0x7fffu + ((a.u >> 16) & 1u)) >> 16;
    union { unsigned short s; __bf16 b; } o; o.s = (unsigned short)r;
    return o.b;
}

// ---------------------------------------------------------------------------
// Weight prep (all 5 weights in ONE launch): W[K][N] -> WT[N][K] bf16
// y<3: plain bf16 (Wq,Wk,Wv); y>=3: hi/lo split (Wfc,Ws2)
// ---------------------------------------------------------------------------
__global__ __launch_bounds__(256) void wprep_kernel(
    const float* __restrict__ Wq, const float* __restrict__ Wk,
    const float* __restrict__ Wv, const float* __restrict__ Wfc,
    const float* __restrict__ Ws2,
    __bf16* __restrict__ WqT, __bf16* __restrict__ WkT, __bf16* __restrict__ WvT,
    __bf16* __restrict__ WfhT, __bf16* __restrict__ WflT,
    __bf16* __restrict__ W2hT, __bf16* __restrict__ W2lT)
{
    const float* W; __bf16* D0; __bf16* D1 = nullptr;
    switch (blockIdx.y) {
        case 0: W = Wq;  D0 = WqT;  break;
        case 1: W = Wk;  D0 = WkT;  break;
        case 2: W = Wv;  D0 = WvT;  break;
        case 3: W = Wfc; D0 = WfhT; D1 = WflT; break;
        default: W = Ws2; D0 = W2hT; D1 = W2lT; break;
    }

    __shared__ float t[64][65];
    const int tid = threadIdx.x;
    const int bx = blockIdx.x & 7;        // col tile (N)
    const int by = blockIdx.x >> 3;       // row tile (K)
    const int r0 = by * 64, c0 = bx * 64;

    #pragma unroll
    for (int p = 0; p < 4; ++p) {
        int r = p * 16 + (tid >> 4);
        int c = (tid & 15) * 4;
        f32x4 v = *(const f32x4*)(W + (size_t)(r0 + r) * 512 + c0 + c);
        t[r][c] = v[0]; t[r][c + 1] = v[1]; t[r][c + 2] = v[2]; t[r][c + 3] = v[3];
    }
    __syncthreads();
    #pragma unroll
    for (int p = 0; p < 4; ++p) {
        int c = p * 16 + (tid >> 4);
        int rc = (tid & 15) * 4;
        if (D1 == nullptr) {
            bf16x4 o;
            #pragma unroll
            for (int m = 0; m < 4; ++m) o[m] = f2bf(t[rc + m][c]);
            *(bf16x4*)(D0 + (size_t)(c0 + c) * 512 + r0 + rc) = o;
        } else {
            bf16x4 oh, ol;
            #pragma unroll
            for (int m = 0; m < 4; ++m) {
                float v = t[rc + m][c];
                __bf16 hi = f2bf(v);
                oh[m] = hi;
                ol[m] = f2bf(v - (float)hi);
            }
            *(bf16x4*)(D0 + (size_t)(c0 + c) * 512 + r0 + rc) = oh;
            *(bf16x4*)(D1 + (size_t)(c0 + c) * 512 + r0 + rc) = ol;
        }
    }
}

// ---------------------------------------------------------------------------
// Merged QKV MFMA GEMM: one launch, 1536 blocks (6/CU), XCD-swizzled.
// z=0: Q->Qb, z=1: K->Kb, z=2: V->VtG (fused transpose epilogue).
// BM=128 BN=64 BK=64; 4 waves (2m x 2n).
// ---------------------------------------------------------------------------
__global__ __launch_bounds__(256) void gemm_qkv3_mfma(
    const float* __restrict__ q, const float* __restrict__ k,
    const float* __restrict__ v,
    const __bf16* __restrict__ WqT, const __bf16* __restrict__ WkT,
    const __bf16* __restrict__ WvT,
    const float* __restrict__ bq, const float* __restrict__ bk,
    const float* __restrict__ bv,
    __bf16* __restrict__ Qb, __bf16* __restrict__ Kb, __bf16* __restrict__ VtG)
{
    // XCD-aware bijective swizzle: 1536 blocks, 8 XCDs, 192 per XCD chunk
    const int f = blockIdx.x;
    const int s = (f & 7) * 192 + (f >> 3);
    const int z   = s >> 9;          // 0..2
    const int rem = s & 511;
    const int bx  = rem & 7;         // col tile
    const int by  = rem >> 3;        // row tile (0..63)

    const float*  A    = (z == 0) ? q   : (z == 1) ? k   : v;
    const __bf16* Bt   = (z == 0) ? WqT : (z == 1) ? WkT : WvT;
    const float*  bias = (z == 0) ? bq  : (z == 1) ? bk  : bv;

    const int tid  = threadIdx.x;
    const int w    = tid >> 6, lane = tid & 63;
    const int quad = lane >> 4, lid = lane & 15;
    const int wm = w >> 1, wn = w & 1;
    const int col0 = bx * 64;
    const int row0 = by * 128;

    __shared__ __bf16 As[128][72];
    __shared__ __bf16 Bs[64][72];

    const f32x4 zero = {0.f, 0.f, 0.f, 0.f};
    f32x4 acc[4][2];
    #pragma unroll
    for (int i = 0; i < 4; ++i)
        #pragma unroll
        for (int j = 0; j < 2; ++j) acc[i][j] = zero;

    for (int kt = 0; kt < 512; kt += 64) {
        __syncthreads();
        {
            const int rr = lane >> 4;
            const int cc = lane & 15;
            #pragma unroll
            for (int p = 0; p < 8; ++p) {
                int r = w * 32 + p * 4 + rr;
                f32x4 vv = *(const f32x4*)(A + (size_t)(row0 + r) * 512 + kt + cc * 4);
                bf16x4 o;
                #pragma unroll
                for (int m = 0; m < 4; ++m) o[m] = f2bf(vv[m]);
                *(bf16x4*)&As[r][cc * 4] = o;
            }
        }
        {
            const int rr = lane >> 3;
            const int cc = lane & 7;
            #pragma unroll
            for (int p = 0; p < 2; ++p) {
                int r = w * 16 + p * 8 + rr;
                *(bf16x8*)&Bs[r][cc * 8] =
                    *(const bf16x8*)(Bt + (size_t)(col0 + r) * 512 + kt + cc * 8);
            }
        }
        __syncthreads();
        #pragma unroll
        for (int ks = 0; ks < 2; ++ks) {
            bf16x8 a[4], b[2];
            #pragma unroll
            for (int i = 0; i < 4; ++i)
                a[i] = *(const bf16x8*)&As[wm * 64 + i * 16 + lid][ks * 32 + quad * 8];
            #pragma unroll
            for (int j = 0; j < 2; ++j)
                b[j] = *(const bf16x8*)&Bs[wn * 32 + j * 16 + lid][ks * 32 + quad * 8];
            #pragma unroll
            for (int i = 0; i < 4; ++i)
                #pragma unroll
                for (int j = 0; j < 2; ++j)
                    acc[i][j] = __builtin_amdgcn_mfma_f32_16x16x32_bf16(a[i], b[j], acc[i][j], 0, 0, 0);
        }
    }

    float bcol[2];
    #pragma unroll
    for (int j = 0; j < 2; ++j) bcol[j] = bias[col0 + wn * 32 + j * 16 + lid];

    if (z < 2) {
        __bf16* C = (z == 0) ? Qb : Kb;
        #pragma unroll
        for (int i = 0; i < 4; ++i)
            #pragma unroll
            for (int j = 0; j < 2; ++j) {
                int colg = col0 + wn * 32 + j * 16 + lid;
                #pragma unroll
                for (int r = 0; r < 4; ++r) {
                    int rowg = row0 + wm * 64 + i * 16 + quad * 4 + r;
                    C[(size_t)rowg * 512 + colg] = f2bf(acc[i][j][r] + bcol[j]);
                }
            }
    } else {
        // V: transpose epilogue through LDS -> VtG[b,h,d,l]
        __syncthreads();
        __bf16 (*Ts)[136] = (__bf16 (*)[136])(&As[0][0]);
        #pragma unroll
        for (int i = 0; i < 4; ++i)
            #pragma unroll
            for (int j = 0; j < 2; ++j) {
                int d = wn * 32 + j * 16 + lid;
                #pragma unroll
                for (int r = 0; r < 4; ++r) {
                    int l = wm * 64 + i * 16 + quad * 4 + r;
                    Ts[d][l] = f2bf(acc[i][j][r] + bcol[j]);
                }
            }
        __syncthreads();
        const int b = row0 >> 10, l0 = row0 & 1023, h = bx;
        const size_t obase = (size_t)((b * 8 + h) * 64) * LLEN;
        #pragma unroll
        for (int p = 0; p < 4; ++p) {
            int cix = tid + p * 256;
            int d = cix >> 4, lc = cix & 15;
            bf16x8 vv = *(const bf16x8*)&Ts[d][lc * 8];
            *(bf16x8*)(VtG + obase + (size_t)d * LLEN + l0 + lc * 8) = vv;
        }
    }
}

// ---------------------------------------------------------------------------
// Split-bf16 3-pass MFMA GEMM, BM=64 BN=64 BK=32 -> 1024 blocks (4/CU),
// XCD-swizzled. 4 waves (2m x 2n), wave tile 32x32.
// ---------------------------------------------------------------------------
__global__ __launch_bounds__(256) void gemm_split_mfma(
    const __bf16* __restrict__ Ahi, const __bf16* __restrict__ Alo,
    const __bf16* __restrict__ Bth, const __bf16* __restrict__ Btl,
    const float* __restrict__ bias, float* __restrict__ C)
{
    const int f = blockIdx.x;
    const int s = (f & 7) * 128 + (f >> 3);
    const int bx = s & 7, by = s >> 3;     // by 0..127
    const int col0 = bx * 64;
    const int row0 = by * 64;

    const int tid  = threadIdx.x;
    const int w    = tid >> 6, lane = tid & 63;
    const int quad = lane >> 4, lid = lane & 15;
    const int wm = w >> 1, wn = w & 1;

    __shared__ __bf16 Ah[64][40];
    __shared__ __bf16 Al[64][40];
    __shared__ __bf16 Bh[64][40];
    __shared__ __bf16 Bl[64][40];

    const f32x4 zero = {0.f, 0.f, 0.f, 0.f};
    f32x4 acc[2][2];
    #pragma unroll
    for (int i = 0; i < 2; ++i)
        #pragma unroll
        for (int j = 0; j < 2; ++j) acc[i][j] = zero;

    const int rs = tid >> 2, cs = tid & 3;

    for (int kt = 0; kt < 512; kt += 32) {
        __syncthreads();
        {
            size_t ga = (size_t)(row0 + rs) * 512 + kt + cs * 8;
            *(bf16x8*)&Ah[rs][cs * 8] = *(const bf16x8*)(Ahi + ga);
            *(bf16x8*)&Al[rs][cs * 8] = *(const bf16x8*)(Alo + ga);
            size_t gb = (size_t)(col0 + rs) * 512 + kt + cs * 8;
            *(bf16x8*)&Bh[rs][cs * 8] = *(const bf16x8*)(Bth + gb);
            *(bf16x8*)&Bl[rs][cs * 8] = *(const bf16x8*)(Btl + gb);
        }
        __syncthreads();
        bf16x8 ah[2], al[2], bh[2], bl[2];
        #pragma unroll
        for (int i = 0; i < 2; ++i) {
            ah[i] = *(const bf16x8*)&Ah[wm * 32 + i * 16 + lid][quad * 8];
            al[i] = *(const bf16x8*)&Al[wm * 32 + i * 16 + lid][quad * 8];
        }
        #pragma unroll
        for (int j = 0; j < 2; ++j) {
            bh[j] = *(const bf16x8*)&Bh[wn * 32 + j * 16 + lid][quad * 8];
            bl[j] = *(const bf16x8*)&Bl[wn * 32 + j * 16 + lid][quad * 8];
        }
        #pragma unroll
        for (int i = 0; i < 2; ++i)
            #pragma unroll
            for (int j = 0; j < 2; ++j) {
                f32x4 t = __builtin_amdgcn_mfma_f32_16x16x32_bf16(al[i], bh[j], acc[i][j], 0, 0, 0);
                t = __builtin_amdgcn_mfma_f32_16x16x32_bf16(ah[i], bl[j], t, 0, 0, 0);
                acc[i][j] = __builtin_amdgcn_mfma_f32_16x16x32_bf16(ah[i], bh[j], t, 0, 0, 0);
            }
    }

    float bcol[2];
    #pragma unroll
    for (int j = 0; j < 2; ++j) bcol[j] = bias[col0 + wn * 32 + j * 16 + lid];
    #pragma unroll
    for (int i = 0; i < 2; ++i)
        #pragma unroll
        for (int j = 0; j < 2; ++j) {
            int colg = col0 + wn * 32 + j * 16 + lid;
            #pragma unroll
            for (int r = 0; r < 4; ++r) {
                int rowg = row0 + wm * 32 + i * 16 + quad * 4 + r;
                C[(size_t)rowg * 512 + colg] = acc[i][j][r] + bcol[j];
            }
        }
}

// ---------------------------------------------------------------------------
// FiLM latent
// ---------------------------------------------------------------------------
__global__ __launch_bounds__(256) void film_latent_kernel(
    const float* __restrict__ latent, const float* __restrict__ Ws1,
    const float* __restrict__ bs1, float* __restrict__ film)
{
    __shared__ float sl[DLAT];
    const int b = blockIdx.x;
    const int tid = threadIdx.x;
    #pragma unroll
    for (int l = 0; l < 2; ++l) {
        int k = tid + l * 256;
        float x = latent[b * DLAT + k];
        sl[k] = x / (1.f + __expf(-x));
    }
    __syncthreads();
    int n = blockIdx.y * 256 + tid;
    float acc = bs1[n];
    for (int k = 0; k < DLAT; ++k)
        acc += sl[k] * Ws1[(size_t)k * 1024 + n];
    film[b * 1024 + n] = acc;
}

// ---------------------------------------------------------------------------
// MFMA attention, double-buffered + async-STAGE + NT attn stores,
// XCD-swizzled so all 128 blocks of one batch b share K/V in one XCD L2.
// ---------------------------------------------------------------------------
__global__ __launch_bounds__(256) void attn_mfma_kernel(
    const __bf16* __restrict__ Qb, const __bf16* __restrict__ Kb,
    const __bf16* __restrict__ VtG, float* __restrict__ attn_out,
    __bf16* __restrict__ Ohi, __bf16* __restrict__ Olo)
{
    const int f = blockIdx.x;
    const int bid = (f & 7) * 128 + (f >> 3);   // XCD swizzle (1024 blocks)
    const int qt = bid & 15;
    const int h  = (bid >> 4) & 7;
    const int b  = bid >> 7;
    const int q0 = qt * 64;
    const int tid = threadIdx.x;
    const int w    = tid >> 6;
    const int lane = tid & 63;
    const int quad = lane >> 4;
    const int lid  = lane & 15;

    __shared__ __bf16 KtS[2][64][72];
    __shared__ __bf16 VtS[2][64][72];
    __shared__ __bf16 PtS[4][16][72];

    const int myq = q0 + w * 16 + lid;
    const __bf16* qptr = Qb + (size_t)(b * LLEN + myq) * DDIM + h * 64 + quad * 8;
    const bf16x8 qf0 = *(const bf16x8*)(qptr);
    const bf16x8 qf1 = *(const bf16x8*)(qptr + 32);

    const size_t kbase = (size_t)(b * LLEN) * DDIM + h * 64;
    const size_t vbase = (size_t)((b * 8 + h) * 64) * LLEN;
    const f32x4 zero = {0.f, 0.f, 0.f, 0.f};
    const float C0 = 0.125f;

    const int sr = tid >> 3;      // 0..31 staging row
    const int sc = tid & 7;       // 0..7  staging 16B chunk

    // ---------------- pass 1: row sums ----------------
    #pragma unroll
    for (int rep = 0; rep < 2; ++rep) {
        int r = sr + rep * 32;
        *(bf16x8*)&KtS[0][r][sc * 8] =
            *(const bf16x8*)(Kb + kbase + (size_t)r * DDIM + sc * 8);
    }
    __syncthreads();

    float rsum = 0.f;
    int cur = 0;
    for (int kt = 0; kt < 16; ++kt) {
        bf16x8 kr0, kr1;
        if (kt < 15) {
            kr0 = *(const bf16x8*)(Kb + kbase + (size_t)((kt + 1) * 64 + sr) * DDIM + sc * 8);
            kr1 = *(const bf16x8*)(Kb + kbase + (size_t)((kt + 1) * 64 + sr + 32) * DDIM + sc * 8);
        }
        #pragma unroll
        for (int st = 0; st < 4; ++st) {
            bf16x8 a0 = *(const bf16x8*)&KtS[cur][st * 16 + lid][quad * 8];
            bf16x8 a1 = *(const bf16x8*)&KtS[cur][st * 16 + lid][32 + quad * 8];
            f32x4 c = __builtin_amdgcn_mfma_f32_16x16x32_bf16(a0, qf0, zero, 0, 0, 0);
            c = __builtin_amdgcn_mfma_f32_16x16x32_bf16(a1, qf1, c, 0, 0, 0);
            #pragma unroll
            for (int r = 0; r < 4; ++r) rsum += __expf(C0 * c[r]);
        }
        if (kt < 15) {
            *(bf16x8*)&KtS[cur ^ 1][sr][sc * 8] = kr0;
            *(bf16x8*)&KtS[cur ^ 1][sr + 32][sc * 8] = kr1;
        }
        __syncthreads();
        cur ^= 1;
    }
    rsum += __shfl_xor(rsum, 16, 64);
    rsum += __shfl_xor(rsum, 32, 64);
    const float rinv = 1.f / rsum;

    // ---------------- pass 2: attn write + PV ----------------
    f32x4 oacc[4] = {zero, zero, zero, zero};
    const size_t abase = ((size_t)((b * 8 + h) * LLEN + myq)) * LLEN;

    #pragma unroll
    for (int rep = 0; rep < 2; ++rep) {
        int r = sr + rep * 32;
        *(bf16x8*)&KtS[0][r][sc * 8] =
            *(const bf16x8*)(Kb + kbase + (size_t)r * DDIM + sc * 8);
        *(bf16x8*)&VtS[0][r][sc * 8] =
            *(const bf16x8*)(VtG + vbase + (size_t)r * LLEN + sc * 8);
    }
    __syncthreads();

    cur = 0;
    for (int kt = 0; kt < 16; ++kt) {
        bf16x8 kr0, kr1, vr0, vr1;
        if (kt < 15) {
            kr0 = *(const bf16x8*)(Kb + kbase + (size_t)((kt + 1) * 64 + sr) * DDIM + sc * 8);
            kr1 = *(const bf16x8*)(Kb + kbase + (size_t)((kt + 1) * 64 + sr + 32) * DDIM + sc * 8);
            vr0 = *(const bf16x8*)(VtG + vbase + (size_t)sr * LLEN + (kt + 1) * 64 + sc * 8);
            vr1 = *(const bf16x8*)(VtG + vbase + (size_t)(sr + 32) * LLEN + (kt + 1) * 64 + sc * 8);
        }
        #pragma unroll
        for (int st = 0; st < 4; ++st) {
            bf16x8 a0 = *(const bf16x8*)&KtS[cur][st * 16 + lid][quad * 8];
            bf16x8 a1 = *(const bf16x8*)&KtS[cur][st * 16 + lid][32 + quad * 8];
            f32x4 c = __builtin_amdgcn_mfma_f32_16x16x32_bf16(a0, qf0, zero, 0, 0, 0);
            c = __builtin_amdgcn_mfma_f32_16x16x32_bf16(a1, qf1, c, 0, 0, 0);
            f32x4 p;
            bf16x4 pk;
            #pragma unroll
            for (int r = 0; r < 4; ++r) {
                p[r] = __expf(C0 * c[r]) * rinv;
                pk[r] = f2bf(p[r]);
            }
            __builtin_nontemporal_store(p, (f32x4*)(attn_out + abase + kt * 64 + st * 16 + quad * 4));
            *(bf16x4*)&PtS[w][lid][st * 16 + quad * 4] = pk;
        }
        asm volatile("s_waitcnt lgkmcnt(0)" ::: "memory");
        #pragma unroll
        for (int kc = 0; kc < 2; ++kc) {
            bf16x8 pa = *(const bf16x8*)&PtS[w][lid][kc * 32 + quad * 8];
            #pragma unroll
            for (int nt = 0; nt < 4; ++nt) {
                bf16x8 vb = *(const bf16x8*)&VtS[cur][nt * 16 + lid][kc * 32 + quad * 8];
                oacc[nt] = __builtin_amdgcn_mfma_f32_16x16x32_bf16(pa, vb, oacc[nt], 0, 0, 0);
            }
        }
        if (kt < 15) {
            *(bf16x8*)&KtS[cur ^ 1][sr][sc * 8] = kr0;
            *(bf16x8*)&KtS[cur ^ 1][sr + 32][sc * 8] = kr1;
            *(bf16x8*)&VtS[cur ^ 1][sr][sc * 8] = vr0;
            *(bf16x8*)&VtS[cur ^ 1][sr + 32][sc * 8] = vr1;
        }
        __syncthreads();
        cur ^= 1;
    }

    // O epilogue: hi/lo bf16 split
    #pragma unroll
    for (int nt = 0; nt < 4; ++nt)
        #pragma unroll
        for (int r = 0; r < 4; ++r) {
            float val = oacc[nt][r];
            __bf16 hi = f2bf(val);
            size_t idx = (size_t)(b * LLEN + q0 + w * 16 + quad * 4 + r) * DDIM + h * 64 + nt * 16 + lid;
            Ohi[idx] = hi;
            Olo[idx] = f2bf(val - (float)hi);
        }
}

// ---------------------------------------------------------------------------
__device__ inline void block_reduce2(float& a, float& b) {
    #pragma unroll
    for (int off = 32; off > 0; off >>= 1) {
        a += __shfl_down(a, off, 64);
        b += __shfl_down(b, off, 64);
    }
    __shared__ float wa[4], wb[4];
    int lane = threadIdx.x & 63, w = threadIdx.x >> 6;
    if (lane == 0) { wa[w] = a; wb[w] = b; }
    __syncthreads();
    if (threadIdx.x == 0) {
        wa[0] = wa[0] + wa[1] + wa[2] + wa[3];
        wb[0] = wb[0] + wb[1] + wb[2] + wb[3];
    }
    __syncthreads();
    a = wa[0];
    b = wb[0];
}

__global__ __launch_bounds__(256) void film_ln_kernel(
    const float* __restrict__ X, const float* __restrict__ en_g,
    const float* __restrict__ en_b, const float* __restrict__ film,
    __bf16* __restrict__ HShi, __bf16* __restrict__ HSlo)
{
    const int row = blockIdx.x;
    const int b = row >> 10;
    const int tid = threadIdx.x;
    const size_t base = (size_t)row * DDIM;

    float x0 = X[base + tid];
    float x1 = X[base + 256 + tid];
    float s = x0 + x1;
    float s2 = x0 * x0 + x1 * x1;
    block_reduce2(s, s2);
    float mean = s * (1.f / 512.f);
    float var = s2 * (1.f / 512.f) - mean * mean;
    float inv = rsqrtf(var + 1e-5f);

    #pragma unroll
    for (int l = 0; l < 2; ++l) {
        int d = tid + l * 256;
        float x = (l == 0) ? x0 : x1;
        float nh = (x - mean) * inv * en_g[d] + en_b[d];
        float sc = film[b * 1024 + d];
        float sh = film[b * 1024 + 512 + d];
        float hv = nh * (1.f + sc) + sh;
        float sv = hv / (1.f + __expf(-hv));
        __bf16 hi = f2bf(sv);
        HShi[base + d] = hi;
        HSlo[base + d] = f2bf(sv - (float)hi);
    }
}

__global__ __launch_bounds__(256) void final_ln_kernel(
    const float* __restrict__ H2, const float* __restrict__ resid,
    const float* __restrict__ g, const float* __restrict__ bta,
    float* __restrict__ out)
{
    const int row = blockIdx.x;
    const int tid = threadIdx.x;
    const size_t base = (size_t)row * DDIM;

    float x0 = H2[base + tid] + resid[base + tid];
    float x1 = H2[base + 256 + tid] + resid[base + 256 + tid];
    float s = x0 + x1;
    float s2 = x0 * x0 + x1 * x1;
    block_reduce2(s, s2);
    float mean = s * (1.f / 512.f);
    float var = s2 * (1.f / 512.f) - mean * mean;
    float inv = rsqrtf(var + 1e-6f);

    #pragma unroll
    for (int l = 0; l < 2; ++l) {
        int d = tid + l * 256;
        float x = (l == 0) ? x0 : x1;
        float o = (x - mean) * inv * g[d] + bta[d];
        __builtin_nontemporal_store(o, out + base + d);
    }
}

// ---------------------------------------------------------------------------
extern "C" void kernel_launch(void* const* d_in, const int* in_sizes, int n_in,
                              void* d_out, int out_size, void* d_ws, size_t ws_size,
                              hipStream_t stream)
{
    const float* q      = (const float*)d_in[0];
    const float* k      = (const float*)d_in[1];
    const float* v      = (const float*)d_in[2];
    const float* latent = (const float*)d_in[3];
    const float* Wq  = (const float*)d_in[4];
    const float* bq  = (const float*)d_in[5];
    const float* Wk  = (const float*)d_in[6];
    const float* bk  = (const float*)d_in[7];
    const float* Wv  = (const float*)d_in[8];
    const float* bv  = (const float*)d_in[9];
    const float* Wfc = (const float*)d_in[10];
    const float* bfc = (const float*)d_in[11];
    const float* Ws1 = (const float*)d_in[12];
    const float* bs1 = (const float*)d_in[13];
    const float* Ws2 = (const float*)d_in[14];
    const float* bs2 = (const float*)d_in[15];
    const float* en_g = (const float*)d_in[16];
    const float* en_b = (const float*)d_in[17];
    const float* ln_g = (const float*)d_in[18];
    const float* ln_b = (const float*)d_in[19];

    float* out  = (float*)d_out;            // [8192, 512]
    float* attn = out + ROWELEM;            // [8, 8, 1024, 1024]

    char* ws = (char*)d_ws;
    __bf16* Qb   = (__bf16*)(ws + 0);              // 8.4 MB
    __bf16* Kb   = (__bf16*)(ws + 8388608);
    __bf16* VtG  = (__bf16*)(ws + 16777216);
    __bf16* Ohi  = (__bf16*)(ws + 25165824);
    __bf16* Olo  = (__bf16*)(ws + 33554432);
    __bf16* WqT  = (__bf16*)(ws + 41943040);       // 512 KB each
    __bf16* WkT  = (__bf16*)(ws + 42467328);
    __bf16* WvT  = (__bf16*)(ws + 42991616);
    __bf16* WfhT = (__bf16*)(ws + 43515904);
    __bf16* WflT = (__bf16*)(ws + 44040192);
    __bf16* W2hT = (__bf16*)(ws + 44564480);
    __bf16* W2lT = (__bf16*)(ws + 45088768);
    float*  film = (float*)(ws + 45613056);        // 32 KB

    // aliases over dead regions:
    float*  F1   = (float*)(ws + 0);               // over Qb+Kb (dead after attn)
    __bf16* HShi = Ohi;                            // O dead after FC gemm
    __bf16* HSlo = Olo;
    float*  H2   = (float*)(ws + 0);               // over F1 (dead after film_ln)

    wprep_kernel<<<dim3(64, 5), 256, 0, stream>>>(
        Wq, Wk, Wv, Wfc, Ws2, WqT, WkT, WvT, WfhT, WflT, W2hT, W2lT);
    film_latent_kernel<<<dim3(BB, 4), 256, 0, stream>>>(latent, Ws1, bs1, film);

    gemm_qkv3_mfma<<<1536, 256, 0, stream>>>(
        q, k, v, WqT, WkT, WvT, bq, bk, bv, Qb, Kb, VtG);

    attn_mfma_kernel<<<1024, 256, 0, stream>>>(Qb, Kb, VtG, attn, Ohi, Olo);

    gemm_split_mfma<<<1024, 256, 0, stream>>>(Ohi, Olo, WfhT, WflT, bfc, F1);
    film_ln_kernel<<<NROW, 256, 0, stream>>>(F1, en_g, en_b, film, HShi, HSlo);
    gemm_split_mfma<<<1024, 256, 0, stream>>>(HShi, HSlo, W2hT, W2lT, bs2, H2);
    final_ln_kernel<<<NROW, 256, 0, stream>>>(H2, q, ln_g, ln_b, out);
}